// Round 8
// baseline (430.703 us; speedup 1.0000x reference)
//
#include <hip/hip_runtime.h>
#include <hip/hip_bf16.h>
#include <stdint.h>

typedef __attribute__((ext_vector_type(8))) __bf16 bf16x8;
typedef __attribute__((ext_vector_type(4))) float  f32x4;

// ---------- bf16 helpers (bf16 pairs packed in uint32, little-endian) ----------
__device__ __forceinline__ float bflo(uint32_t p){ return __uint_as_float(p << 16); }
__device__ __forceinline__ float bfhi(uint32_t p){ return __uint_as_float(p & 0xffff0000u); }
__device__ __forceinline__ uint16_t f2bf(float f){
    uint32_t u = __float_as_uint(f);
    uint32_t r = (u + 0x7fffu + ((u >> 16) & 1u)) >> 16;   // RNE
    return (uint16_t)r;
}
__device__ __forceinline__ uint32_t packbf(float a, float b){
    return (uint32_t)f2bf(a) | ((uint32_t)f2bf(b) << 16);
}
__device__ __forceinline__ f32x4 MFMA(bf16x8 a, bf16x8 b, f32x4 c){
    return __builtin_amdgcn_mfma_f32_16x16x32_bf16(a, b, c, 0, 0, 0);
}

// Xbf (layer-1 bf16 input) lives in the FIRST HALF of each f32 Emb row:
//   Emb u32 [row*128, row*128+64).  (Mean buffer eliminated: gather fused into gemm.)

// ---------- CSR build ----------
__global__ void k_deg(const int* __restrict__ dst, int* __restrict__ counts, int E){
    int e = blockIdx.x * 256 + threadIdx.x;
    if (e < E) atomicAdd(&counts[dst[e]], 1);
}

__global__ void k_scan1(const int* __restrict__ counts, int* __restrict__ bsums, int N){
    __shared__ int lds[256];
    int t = threadIdx.x;
    int base = blockIdx.x * 2048 + t * 8;
    int s = 0;
    #pragma unroll
    for (int i = 0; i < 8; ++i){ int idx = base + i; s += (idx < N) ? counts[idx] : 0; }
    lds[t] = s; __syncthreads();
    for (int off = 128; off > 0; off >>= 1){
        if (t < off) lds[t] += lds[t + off];
        __syncthreads();
    }
    if (t == 0) bsums[blockIdx.x] = lds[0];
}

__global__ void k_scan2(int* bsums, int NB){
    int run = 0;
    for (int i = 0; i < NB; ++i){ int v = bsums[i]; bsums[i] = run; run += v; }
}

__global__ void k_scan3(const int* __restrict__ counts, const int* __restrict__ bsums,
                        int* __restrict__ offs, int N){
    __shared__ int lds[256];
    int t = threadIdx.x;
    int base = blockIdx.x * 2048 + t * 8;
    int local[8];
    int s = 0;
    #pragma unroll
    for (int i = 0; i < 8; ++i){
        int idx = base + i;
        int v = (idx < N) ? counts[idx] : 0;
        local[i] = v; s += v;
    }
    lds[t] = s; __syncthreads();
    for (int off = 1; off < 256; off <<= 1){
        int v = (t >= off) ? lds[t - off] : 0;
        __syncthreads();
        lds[t] += v;
        __syncthreads();
    }
    int run = bsums[blockIdx.x] + (lds[t] - s);
    #pragma unroll
    for (int i = 0; i < 8; ++i){
        int idx = base + i;
        if (idx < N){ offs[idx] = run; run += local[i]; }
    }
}

__global__ void k_fill(const int* __restrict__ src, const int* __restrict__ dst,
                       const int* __restrict__ offs, int* __restrict__ cursor,
                       int* __restrict__ ssrc, int E){
    int e = blockIdx.x * 256 + threadIdx.x;
    if (e < E){
        int d = dst[e];
        int p = atomicAdd(&cursor[d], 1);
        ssrc[offs[d] + p] = src[e];
    }
}

// ---------- x -> bf16 hi (into Emb first half) + bf16 lo residual ----------
__global__ __launch_bounds__(256) void k_x2bf(const float* __restrict__ X,
        uint32_t* __restrict__ XbfE, uint32_t* __restrict__ Xlo, int N){
    int i = blockIdx.x * 256 + threadIdx.x;          // 2-pair chunk, total N*32
    if (i >= N * 32) return;
    int row = i >> 5, l = i & 31;
    float4 v = *(const float4*)(X + (size_t)i * 4);
    uint16_t h0 = f2bf(v.x), h1 = f2bf(v.y), h2 = f2bf(v.z), h3 = f2bf(v.w);
    float r0 = v.x - __uint_as_float((uint32_t)h0 << 16);
    float r1 = v.y - __uint_as_float((uint32_t)h1 << 16);
    float r2 = v.z - __uint_as_float((uint32_t)h2 << 16);
    float r3 = v.w - __uint_as_float((uint32_t)h3 << 16);
    uint2 hi; hi.x = (uint32_t)h0 | ((uint32_t)h1 << 16);
    hi.y = (uint32_t)h2 | ((uint32_t)h3 << 16);
    uint2 lo; lo.x = packbf(r0, r1); lo.y = packbf(r2, r3);
    *(uint2*)(XbfE + (size_t)row * 128 + l * 2) = hi;
    *(uint2*)(Xlo  + (size_t)row * 64  + l * 2) = lo;
}

// ---------- weight prep: packed + bank-swizzled layout for LDS staging ----------
// Wpk u16 layout: [kt(8)][sel(2: hi,lo)][slot(512)][e(8)]
//   slot(c,g) = 4*c + (g ^ ((c>>1)&3))   (bank swizzle: octet of lanes -> 8 distinct
//   16B slots -> all 32 banks once per octet on ds_read_b128)
// source: k<128 -> Wl[k][c], k>=128 -> scale*Wr[k-128][c];  k = kt*32 + g*8 + e
__global__ void k_wprep(const float* __restrict__ Wl, const float* __restrict__ Wr,
                        const float* __restrict__ scale,
                        uint16_t* __restrict__ Wpk){
    int idx = blockIdx.x * 256 + threadIdx.x;        // [0, 32768) = c*256 + k
    int c = idx >> 8, k = idx & 255;
    float v;
    if (k < 128){
        v = Wl[k * 128 + c];
    } else {
        v = Wr[(k - 128) * 128 + c];
        if (scale) v *= scale[k - 128];
    }
    uint16_t h = f2bf(v);
    float r = v - __uint_as_float((uint32_t)h << 16);
    int kt = k >> 5, kk = k & 31;
    int g = kk >> 3, e = kk & 7;
    int slot = (c << 2) | (g ^ ((c >> 1) & 3));
    size_t base = (size_t)kt * 8192 + (size_t)slot * 8 + e;
    Wpk[base]        = h;
    Wpk[base + 4096] = f2bf(r);
}

// stage one quarter (32 KiB: 4 kt of one sel) of B into sB (4-wave version).
// LDS dest is wave-uniform base (+ lane*16 by HW); global src is per-lane.
__device__ __forceinline__ void stage4(const uint32_t* Wpk, uint32_t (*sB)[2048],
                                       int wid, int lane, int sel, int half){
    #pragma unroll
    for (int i = 0; i < 8; ++i){
        int ch = wid * 8 + i;                        // 32 chunks of 1 KiB
        int ktv = ch >> 3, part = ch & 7;
        __builtin_amdgcn_global_load_lds(
            Wpk + (size_t)(half * 4 + ktv) * 4096 + sel * 2048 + part * 256 + lane * 4,
            &sB[ktv][part * 256], 16, 0, 0);
    }
}

// ---------- FUSED gather + MFMA dual-GEMM (K=256 = [mean|own]) + L2-normalize ----
// 256 threads = 4 waves; each wave owns 16 rows (one m-tile), all 128 cols.
// R7 post-mortem: gemm is latency-bound and immune to occupancy (4 variants all
// 55-58us); k_agg (separate dispatch, ~45us/layer) is the same kind of latency.
// FUSION: each wave gathers its 16 rows' neighbor-means (CSR walk, 16-lane groups
// load full 256B rows) into a swizzled LDS tile sM BEFORE barrier 1, overlapping
// the weight staging; the mean A-fragments then come from conflict-free
// ds_read_b128 (slot XOR row&7 -> 2-way = free).  Kills both k_agg dispatches
// and the mean write+read roundtrip (~50MB).
// sM layout: [wave][row r][16 slots of 16B]; logical slot s (u32 cols 4s..4s+3,
// channels 8s..8s+7) stored at phys slot s ^ (r&7).
// B frag:  swizzled Wpk slot; gx = g ^ ((l15>>1)&3)  (conflict-free)
// C/D:     col = lane&15, row = 4*(lane>>4) + reg    (m89-verified)
// MODE 0: own+gather src = Xbf (Emb rows, stride 128) (+Xlo correction on hi);
//         out=relu(norm(.)); Hbf store + BN sums.
// MODE 1: own+gather src = Hbf (stride 64), BN folded into gather/Wpk/bias;
//         out=norm(.); Emb f32 + preds.
template<int MODE>
__global__ __launch_bounds__(256) void k_gemm(
        const uint32_t* Own,                 // MODE0: Xbf in Emb rows; MODE1: Hbf
        const uint32_t* OwnLo,               // MODE0 only: Xlo (stride 64; aliases HbfOut)
        const int* __restrict__ offs, const int* __restrict__ counts,
        const int* __restrict__ ssrc,
        const float* __restrict__ bnscale, const float* __restrict__ bnshift, // MODE1 gather fold
        const uint32_t* __restrict__ Wpk,    // packed+swizzled [kt][hi/lo][512 slots][8] u16
        const float* __restrict__ bias,      // [128] effective bias
        uint32_t* HbfOut,                    // MODE0 out (aliases OwnLo; alias-safe per-wave)
        float* Emb,                          // MODE1 out
        float* __restrict__ bnsum, float* __restrict__ bnsumsq,             // MODE0
        const float* __restrict__ fcW, const float* __restrict__ fcb,       // MODE1
        float* __restrict__ preds, int N){
    __shared__ uint32_t __align__(16) sB[4][2048];   // 32 KiB weights; aliased by lsum/lsq at end
    __shared__ uint32_t __align__(16) sM[4][16][64]; // 16 KiB per-wave mean tiles
    const int lane = threadIdx.x & 63;
    const int wid  = threadIdx.x >> 6;               // 0..3
    const int l15  = lane & 15;
    const int g    = lane >> 4;                      // 0..3 (n-slot group AND gather row-group)
    const int gx4  = (g ^ ((l15 >> 1) & 3)) * 4;     // swizzled Wpk 16B sub-slot (u32 units)
    const int ostr = (MODE == 0) ? 128 : 64;
    const int wrow = blockIdx.x * 64 + wid * 16;     // this wave's 16-row m-tile

    stage4(Wpk, sB, wid, lane, 0, 0);                // quarter 1: hi, kt 0-3 (issue early)

    int ar0 = wrow + l15; if (ar0 >= N) ar0 = N - 1; // clamped dup rows: discarded

    // own A fragments (independent global loads; overlap staging + gather)
    const uint32_t* op0 = Own + (size_t)ar0 * ostr + g * 4;
    bf16x8 ao[4];
    #pragma unroll
    for (int kq = 0; kq < 4; ++kq) ao[kq] = *(const bf16x8*)(op0 + kq * 16);
    bf16x8 xl[4];
    if (MODE == 0){
        #pragma unroll
        for (int kq = 0; kq < 4; ++kq)
            xl[kq] = *(const bf16x8*)(OwnLo + (size_t)ar0 * 64 + g * 4 + kq * 16);
    }

    // per-row CSR meta via lanes 0..15 (broadcast via shfl in the r-loop)
    int cntv = counts[ar0];
    int offv = offs[ar0];

    // BN fold constants for gather (channel-indexed, same for all rows)
    float sc[8], sh[8];
    if (MODE == 1){
        int c0 = l15 * 8;
        float4 s0 = *(const float4*)(bnscale + c0);
        float4 s1 = *(const float4*)(bnscale + c0 + 4);
        float4 h0 = *(const float4*)(bnshift + c0);
        float4 h1 = *(const float4*)(bnshift + c0 + 4);
        sc[0]=s0.x; sc[1]=s0.y; sc[2]=s0.z; sc[3]=s0.w;
        sc[4]=s1.x; sc[5]=s1.y; sc[6]=s1.z; sc[7]=s1.w;
        sh[0]=h0.x; sh[1]=h0.y; sh[2]=h0.z; sh[3]=h0.w;
        sh[4]=h1.x; sh[5]=h1.y; sh[6]=h1.z; sh[7]=h1.w;
    }

    // ---- fused gather: neighbor means for this wave's 16 rows -> sM[wid] ----
    const uint32_t* srcb = Own + l15 * 4;            // lane covers channels l15*8..+7
    for (int r = 0; r < 16; ++r){
        int cnt = __shfl(cntv, r, 64);
        int off = __shfl(offv, r, 64);
        if (cnt < 0) cnt = 0;
        float a[8];
        #pragma unroll
        for (int i = 0; i < 8; ++i) a[i] = 0.f;
        int j = 0;
        for (; j + 8 <= cnt; j += 8){                // 8 rows in flight (2 x 4 groups)
            int s0 = ssrc[off + j + g];
            int s1 = ssrc[off + j + 4 + g];
            s0 = (s0 < 0) ? 0 : ((s0 >= N) ? (N - 1) : s0);
            s1 = (s1 < 0) ? 0 : ((s1 >= N) ? (N - 1) : s1);
            uint4 v0 = *(const uint4*)(srcb + (size_t)s0 * ostr);
            uint4 v1 = *(const uint4*)(srcb + (size_t)s1 * ostr);
            a[0] += bflo(v0.x) + bflo(v1.x); a[1] += bfhi(v0.x) + bfhi(v1.x);
            a[2] += bflo(v0.y) + bflo(v1.y); a[3] += bfhi(v0.y) + bfhi(v1.y);
            a[4] += bflo(v0.z) + bflo(v1.z); a[5] += bfhi(v0.z) + bfhi(v1.z);
            a[6] += bflo(v0.w) + bflo(v1.w); a[7] += bfhi(v0.w) + bfhi(v1.w);
        }
        int rem = cnt - j;
        if (rem > 0){
            if (g < rem){
                int s0 = ssrc[off + j + g];
                s0 = (s0 < 0) ? 0 : ((s0 >= N) ? (N - 1) : s0);
                uint4 v0 = *(const uint4*)(srcb + (size_t)s0 * ostr);
                a[0] += bflo(v0.x); a[1] += bfhi(v0.x);
                a[2] += bflo(v0.y); a[3] += bfhi(v0.y);
                a[4] += bflo(v0.z); a[5] += bfhi(v0.z);
                a[6] += bflo(v0.w); a[7] += bfhi(v0.w);
            }
            if (rem > 4 && g < rem - 4){
                int s1 = ssrc[off + j + 4 + g];
                s1 = (s1 < 0) ? 0 : ((s1 >= N) ? (N - 1) : s1);
                uint4 v1 = *(const uint4*)(srcb + (size_t)s1 * ostr);
                a[0] += bflo(v1.x); a[1] += bfhi(v1.x);
                a[2] += bflo(v1.y); a[3] += bfhi(v1.y);
                a[4] += bflo(v1.z); a[5] += bfhi(v1.z);
                a[6] += bflo(v1.w); a[7] += bfhi(v1.w);
            }
        }
        // reduce across the 4 row-groups
        #pragma unroll
        for (int i = 0; i < 8; ++i){
            a[i] += __shfl_xor(a[i], 16, 64);
            a[i] += __shfl_xor(a[i], 32, 64);
        }
        float inv = 1.0f / fmaxf((float)cnt, 1.0f);
        #pragma unroll
        for (int i = 0; i < 8; ++i) a[i] *= inv;
        if (MODE == 1){
            if (cnt > 0){                            // ref: zero-degree mean == 0
                #pragma unroll
                for (int i = 0; i < 8; ++i) a[i] = a[i] * sc[i] + sh[i];
            } else {
                #pragma unroll
                for (int i = 0; i < 8; ++i) a[i] = 0.f;
            }
        }
        if (g == 0){                                 // group 0 writes the packed row
            uint4 o;
            o.x = packbf(a[0], a[1]); o.y = packbf(a[2], a[3]);
            o.z = packbf(a[4], a[5]); o.w = packbf(a[6], a[7]);
            *(uint4*)&sM[wid][r][(l15 ^ (r & 7)) * 4] = o;   // phys slot = l15 ^ (r&7)
        }
    }

    f32x4 acc[8];
    const f32x4 zero = {0.f, 0.f, 0.f, 0.f};
    #pragma unroll
    for (int t = 0; t < 8; ++t) acc[t] = zero;

#define COMPUTE_MEAN()                                                        \
    _Pragma("unroll")                                                         \
    for (int kk = 0; kk < 4; ++kk){                                           \
        bf16x8 aq = *(const bf16x8*)&sM[wid][l15][((kk * 4 + g) ^ (l15 & 7)) * 4]; \
        _Pragma("unroll")                                                     \
        for (int t = 0; t < 8; ++t){                                          \
            bf16x8 bq = *(const bf16x8*)(&sB[kk][(t * 16 + l15) * 16 + gx4]); \
            acc[t] = MFMA(aq, bq, acc[t]);                                    \
        }                                                                     \
    }
#define COMPUTE_OWN(ADD_XLO)                                                  \
    _Pragma("unroll")                                                         \
    for (int kk = 0; kk < 4; ++kk){                                           \
        _Pragma("unroll")                                                     \
        for (int t = 0; t < 8; ++t){                                          \
            bf16x8 bq = *(const bf16x8*)(&sB[kk][(t * 16 + l15) * 16 + gx4]); \
            acc[t] = MFMA(ao[kk], bq, acc[t]);                                \
            if (ADD_XLO) acc[t] = MFMA(xl[kk], bq, acc[t]);                   \
        }                                                                     \
    }

    __syncthreads();                                 // sM written + q1 staged
    COMPUTE_MEAN();                                  // hi, kt 0-3 (mean half)
    __syncthreads();
    stage4(Wpk, sB, wid, lane, 0, 1);                // quarter 2: hi, kt 4-7
    __syncthreads();
    COMPUTE_OWN((MODE == 0));                        // hi, kt 4-7 (own half, +xlo)
    __syncthreads();
    stage4(Wpk, sB, wid, lane, 1, 0);                // quarter 3: lo, kt 0-3
    __syncthreads();
    COMPUTE_MEAN();                                  // lo, kt 0-3 (mean half)
    __syncthreads();
    stage4(Wpk, sB, wid, lane, 1, 1);                // quarter 4: lo, kt 4-7
    __syncthreads();
    COMPUTE_OWN(false);                              // lo, kt 4-7
#undef COMPUTE_MEAN
#undef COMPUTE_OWN

    // ---- epilogue ----
    float bv[8];
    #pragma unroll
    for (int t = 0; t < 8; ++t) bv[t] = bias[t * 16 + l15];

    float fw[4]; float fb = 0.f;
    if (MODE == 1){
        #pragma unroll
        for (int t = 0; t < 4; ++t) fw[t] = fcW[t * 16 + l15];
        fb = fcb[0];
    }

    float pbs[8], pbq[8];
    #pragma unroll
    for (int t = 0; t < 8; ++t){ pbs[t] = 0.f; pbq[t] = 0.f; }

    #pragma unroll
    for (int j = 0; j < 4; ++j){
        int orow = wrow + 4 * g + j;
        bool valid = orow < N;
        float o[8]; float ss = 0.f;
        #pragma unroll
        for (int t = 0; t < 8; ++t){
            o[t] = acc[t][j] + bv[t];
            ss += o[t] * o[t];
        }
        ss += __shfl_xor(ss, 1, 64);
        ss += __shfl_xor(ss, 2, 64);
        ss += __shfl_xor(ss, 4, 64);
        ss += __shfl_xor(ss, 8, 64);
        float inv = 1.0f / fmaxf(sqrtf(ss), 1e-12f);
        if (MODE == 0){
            #pragma unroll
            for (int t = 0; t < 8; ++t){
                float v = fmaxf(o[t] * inv, 0.f);
                float pv = __shfl_xor(v, 1, 64);              // partner col (uniform exec)
                if (valid){
                    pbs[t] += v; pbq[t] += v * v;
                    if (!(lane & 1))
                        HbfOut[(size_t)orow * 64 + t * 8 + (l15 >> 1)] = packbf(v, pv);
                }
            }
        } else {
            float p = 0.f;
            #pragma unroll
            for (int t = 0; t < 8; ++t){
                float v = o[t] * inv;
                if (valid) Emb[(size_t)orow * 128 + t * 16 + l15] = v;
                if (t < 4) p += v * fw[t];
            }
            p += __shfl_xor(p, 1, 64);
            p += __shfl_xor(p, 2, 64);
            p += __shfl_xor(p, 4, 64);
            p += __shfl_xor(p, 8, 64);
            if (valid && l15 == 0) preds[orow] = p + fb;
        }
    }

    if (MODE == 0){
        float* lsum = (float*)&sB[0][0];             // sB dead after last compute
        float* lsq  = lsum + 128;
        #pragma unroll
        for (int t = 0; t < 8; ++t){
            pbs[t] += __shfl_xor(pbs[t], 16, 64);
            pbs[t] += __shfl_xor(pbs[t], 32, 64);
            pbq[t] += __shfl_xor(pbq[t], 16, 64);
            pbq[t] += __shfl_xor(pbq[t], 32, 64);
        }
        __syncthreads();                             // all waves done reading sB
        if (threadIdx.x < 128){ lsum[threadIdx.x] = 0.f; lsq[threadIdx.x] = 0.f; }
        __syncthreads();
        if (lane < 16){
            #pragma unroll
            for (int t = 0; t < 8; ++t){
                atomicAdd(&lsum[t * 16 + lane], pbs[t]);
                atomicAdd(&lsq [t * 16 + lane], pbq[t]);
            }
        }
        __syncthreads();
        if (threadIdx.x < 128){
            atomicAdd(&bnsum[threadIdx.x],   lsum[threadIdx.x]);
            atomicAdd(&bnsumsq[threadIdx.x], lsq[threadIdx.x]);
        }
    }
}

// ---------- BN finalize + effective layer-2 bias (b2 + shift @ W2r) ----------
__global__ void k_bnfinal(const float* __restrict__ bnsum, const float* __restrict__ bnsumsq,
                          const float* __restrict__ gamma, const float* __restrict__ beta,
                          const float* __restrict__ W2r, const float* __restrict__ b2,
                          float* __restrict__ scale, float* __restrict__ shift,
                          float* __restrict__ bias2, int N){
    __shared__ float sh_l[128];
    int t = threadIdx.x;
    float invN = 1.0f / (float)N;
    float mu  = bnsum[t] * invN;
    float var = fmaxf(bnsumsq[t] * invN - mu * mu, 0.f);
    float istd = 1.0f / sqrtf(var + 1e-5f);
    float sc = gamma[t] * istd;
    float sf = beta[t] - mu * sc;
    scale[t] = sc; shift[t] = sf; sh_l[t] = sf;
    __syncthreads();
    float acc = b2[t];
    for (int k = 0; k < 128; ++k) acc += sh_l[k] * W2r[k * 128 + t];
    bias2[t] = acc;
}

__global__ void k_sent(float* __restrict__ preds, int N, float val){
    int i = blockIdx.x * 256 + threadIdx.x;
    if (i < N) preds[i] = val;
}

// ---------- launch ----------
extern "C" void kernel_launch(void* const* d_in, const int* in_sizes, int n_in,
                              void* d_out, int out_size, void* d_ws, size_t ws_size,
                              hipStream_t stream){
    const int N = in_sizes[0] / 128;
    const int E = in_sizes[1] / 2;

    const float* x    = (const float*)d_in[0];
    const int*   ei   = (const int*)d_in[1];
    const int*   src  = ei;
    const int*   dst  = ei + E;
    const float* W1l  = (const float*)d_in[2];
    const float* b1   = (const float*)d_in[3];
    const float* W1r  = (const float*)d_in[4];
    const float* gam  = (const float*)d_in[5];
    const float* bet  = (const float*)d_in[6];
    const float* W2l  = (const float*)d_in[7];
    const float* b2   = (const float*)d_in[8];
    const float* W2r  = (const float*)d_in[9];
    const float* fcW  = (const float*)d_in[10];
    const float* fcb  = (const float*)d_in[11];

    float* preds = (float*)d_out;                 // f32 [N]
    float* Emb   = preds + N;                     // f32 [N,128]
    uint32_t* EmbU = (uint32_t*)Emb;              // Xbf (1st half) scratch

    char* w = (char*)d_ws;
    auto carve = [&](size_t bytes){ char* p = w; w += (bytes + 255) & ~(size_t)255; return p; };
    int*   counts  = (int*)  carve((size_t)N * 8);   // counts[N] + cursor[N], one memset
    int*   cursor  = counts + N;
    int*   offs    = (int*)  carve((size_t)N * 4);
    int*   bsums   = (int*)  carve(256 * 4);
    float* bnsum   = (float*)carve(128 * 4);      // contiguous with bnsumsq (one memset)
    float* bnsumsq = (float*)carve(128 * 4);
    float* bnscale = (float*)carve(128 * 4);
    float* bnshift = (float*)carve(128 * 4);
    float* bias2   = (float*)carve(128 * 4);
    int*   ssrc    = (int*)  carve((size_t)E * 4);
    uint32_t* HbfXlo = (uint32_t*)carve((size_t)N * 256);  // Xlo then Hbf (overlay, alias-safe)
    uint16_t* Wpk1 = (uint16_t*)carve(131072);    // packed+swizzled [kt][hi/lo][512][8]
    uint16_t* Wpk2 = (uint16_t*)carve(131072);
    size_t need = (size_t)(w - (char*)d_ws);
    if (ws_size < need){
        float val = 1024.f + 4.f * (float)((ws_size >> 20) > 255 ? 255 : (ws_size >> 20));
        k_sent<<<(N + 255) / 256, 256, 0, stream>>>(preds, N, val);
        return;
    }

    hipMemsetAsync(counts, 0, (size_t)N * 8, stream);
    hipMemsetAsync(bnsum,  0, 1024, stream);

    const int eb = (E + 255) / 256;
    const int NB = (N + 2047) / 2048;
    const int gb = (N + 63) / 64;
    const int xb = (N * 32 + 255) / 256;

    k_deg  <<<eb, 256, 0, stream>>>(dst, counts, E);
    k_scan1<<<NB, 256, 0, stream>>>(counts, bsums, N);
    k_scan2<<<1,    1, 0, stream>>>(bsums, NB);
    k_scan3<<<NB, 256, 0, stream>>>(counts, bsums, offs, N);
    k_fill <<<eb, 256, 0, stream>>>(src, dst, offs, cursor, ssrc, E);

    k_x2bf <<<xb, 256, 0, stream>>>(x, EmbU, HbfXlo, N);
    k_wprep<<<128, 256, 0, stream>>>(W1l, W1r, nullptr, Wpk1);

    // layer 1 (gather fused into gemm)
    k_gemm<0><<<gb, 256, 0, stream>>>(EmbU, HbfXlo, offs, counts, ssrc,
                                      nullptr, nullptr,
                                      (const uint32_t*)Wpk1, b1,
                                      HbfXlo, nullptr, bnsum, bnsumsq,
                                      nullptr, nullptr, nullptr, N);
    k_bnfinal<<<1, 128, 0, stream>>>(bnsum, bnsumsq, gam, bet, W2r, b2,
                                     bnscale, bnshift, bias2, N);
    k_wprep<<<128, 256, 0, stream>>>(W2l, W2r, bnscale, Wpk2);

    // layer 2 (gather fused into gemm)
    k_gemm<1><<<gb, 256, 0, stream>>>(HbfXlo, nullptr, offs, counts, ssrc,
                                      bnscale, bnshift,
                                      (const uint32_t*)Wpk2, bias2,
                                      nullptr, Emb, nullptr, nullptr,
                                      fcW, fcb, preds, N);
}

// Round 9
// 339.917 us; speedup vs baseline: 1.2671x; 1.2671x over previous
//
#include <hip/hip_runtime.h>
#include <hip/hip_bf16.h>
#include <stdint.h>

typedef __attribute__((ext_vector_type(8))) __bf16 bf16x8;
typedef __attribute__((ext_vector_type(4))) float  f32x4;

// ---------- bf16 helpers (bf16 pairs packed in uint32, little-endian) ----------
__device__ __forceinline__ float bflo(uint32_t p){ return __uint_as_float(p << 16); }
__device__ __forceinline__ float bfhi(uint32_t p){ return __uint_as_float(p & 0xffff0000u); }
__device__ __forceinline__ uint16_t f2bf(float f){
    uint32_t u = __float_as_uint(f);
    uint32_t r = (u + 0x7fffu + ((u >> 16) & 1u)) >> 16;   // RNE
    return (uint16_t)r;
}
__device__ __forceinline__ uint32_t packbf(float a, float b){
    return (uint32_t)f2bf(a) | ((uint32_t)f2bf(b) << 16);
}
__device__ __forceinline__ f32x4 MFMA(bf16x8 a, bf16x8 b, f32x4 c){
    return __builtin_amdgcn_mfma_f32_16x16x32_bf16(a, b, c, 0, 0, 0);
}

// Mean buffer lives in the SECOND HALF of each f32 Emb row (u32 units);
// Xbf (layer-1 bf16 input) lives in the FIRST HALF.

// ---------- weight pack helper (shared by k_prep / k_bnwprep2) ----------
// Wpk u16 layout: [kt(8)][sel(2: hi,lo)][slot(512)][e(8)]
//   slot(c,g) = 4*c + (g ^ ((c>>1)&3))   (bank swizzle for conflict-free ds_read_b128)
__device__ __forceinline__ void wpack_one(uint16_t* __restrict__ Wpk, int idx, float v){
    int c = idx >> 8, k = idx & 255;
    uint16_t h = f2bf(v);
    float r = v - __uint_as_float((uint32_t)h << 16);
    int kt = k >> 5, kk = k & 31;
    int g = kk >> 3, e = kk & 7;
    int slot = (c << 2) | (g ^ ((c >> 1) & 3));
    size_t base = (size_t)kt * 8192 + (size_t)slot * 8 + e;
    Wpk[base]        = h;
    Wpk[base + 4096] = f2bf(r);
}

// ---------- fused prep: wprep1 (blocks 0..127) | x2bf | deg  + bnsum zeroing ----
__global__ __launch_bounds__(256) void k_prep(
        const float* __restrict__ X, uint32_t* __restrict__ XbfE, uint32_t* __restrict__ Xlo,
        const int* __restrict__ dst, int* __restrict__ counts,
        const float* __restrict__ W1l, const float* __restrict__ W1r,
        uint16_t* __restrict__ Wpk1, float* __restrict__ bnsum,
        int N, int E, int xb){
    int bid = blockIdx.x, tid = threadIdx.x;
    if (bid < 128){
        if (bid == 0) bnsum[tid] = 0.f;              // bnsum[128]+bnsumsq[128] contiguous
        int idx = bid * 256 + tid;                   // [0, 32768) = c*256 + k
        int k = idx & 255, c = idx >> 8;
        float v = (k < 128) ? W1l[k * 128 + c] : W1r[(k - 128) * 128 + c];
        wpack_one(Wpk1, idx, v);
    } else if (bid < 128 + xb){
        int i = (bid - 128) * 256 + tid;             // 2-pair chunk, total N*32
        if (i < N * 32){
            int row = i >> 5, l = i & 31;
            float4 v = *(const float4*)(X + (size_t)i * 4);
            uint16_t h0 = f2bf(v.x), h1 = f2bf(v.y), h2 = f2bf(v.z), h3 = f2bf(v.w);
            float r0 = v.x - __uint_as_float((uint32_t)h0 << 16);
            float r1 = v.y - __uint_as_float((uint32_t)h1 << 16);
            float r2 = v.z - __uint_as_float((uint32_t)h2 << 16);
            float r3 = v.w - __uint_as_float((uint32_t)h3 << 16);
            uint2 hi; hi.x = (uint32_t)h0 | ((uint32_t)h1 << 16);
            hi.y = (uint32_t)h2 | ((uint32_t)h3 << 16);
            uint2 lo; lo.x = packbf(r0, r1); lo.y = packbf(r2, r3);
            *(uint2*)(XbfE + (size_t)row * 128 + l * 2) = hi;
            *(uint2*)(Xlo  + (size_t)row * 64  + l * 2) = lo;
        }
    } else {
        int e = (bid - 128 - xb) * 256 + tid;
        if (e < E) atomicAdd(&counts[dst[e]], 1);
    }
}

// ---------- CSR scans ----------
__global__ void k_scan1(const int* __restrict__ counts, int* __restrict__ bsums, int N){
    __shared__ int lds[256];
    int t = threadIdx.x;
    int base = blockIdx.x * 2048 + t * 8;
    int s = 0;
    #pragma unroll
    for (int i = 0; i < 8; ++i){ int idx = base + i; s += (idx < N) ? counts[idx] : 0; }
    lds[t] = s; __syncthreads();
    for (int off = 128; off > 0; off >>= 1){
        if (t < off) lds[t] += lds[t + off];
        __syncthreads();
    }
    if (t == 0) bsums[blockIdx.x] = lds[0];
}

// scan3 now also computes its own prefix of bsums (replaces k_scan2): one wave
// reads bsums[0..bid) (NB<=64) and shfl-reduces.
__global__ void k_scan3(const int* __restrict__ counts, const int* __restrict__ bsums,
                        int* __restrict__ offs, int N){
    __shared__ int lds[256];
    __shared__ int base_s;
    int t = threadIdx.x;
    if (t < 64){
        int s2 = 0;
        for (int i = t; i < (int)blockIdx.x; i += 64) s2 += bsums[i];
        #pragma unroll
        for (int m = 32; m >= 1; m >>= 1) s2 += __shfl_xor(s2, m, 64);
        if (t == 0) base_s = s2;
    }
    int base = blockIdx.x * 2048 + t * 8;
    int local[8];
    int s = 0;
    #pragma unroll
    for (int i = 0; i < 8; ++i){
        int idx = base + i;
        int v = (idx < N) ? counts[idx] : 0;
        local[i] = v; s += v;
    }
    lds[t] = s; __syncthreads();                     // also publishes base_s
    for (int off = 1; off < 256; off <<= 1){
        int v = (t >= off) ? lds[t - off] : 0;
        __syncthreads();
        lds[t] += v;
        __syncthreads();
    }
    int run = base_s + (lds[t] - s);
    #pragma unroll
    for (int i = 0; i < 8; ++i){
        int idx = base + i;
        if (idx < N){ offs[idx] = run; run += local[i]; }
    }
}

__global__ void k_fill(const int* __restrict__ src, const int* __restrict__ dst,
                       const int* __restrict__ offs, int* __restrict__ cursor,
                       int* __restrict__ ssrc, int E){
    int e = blockIdx.x * 256 + threadIdx.x;
    if (e < E){
        int d = dst[e];
        int p = atomicAdd(&cursor[d], 1);
        ssrc[offs[d] + p] = src[e];
    }
}

// ---------- neighbor mean: one wave per node; 4 rows per wave-load (uint4) --------
// 16-lane group q loads full 256B row of neighbor (j+q); 8 rows in flight per iter.
// Cross-group shfl reduce at end. MODE 1 folds BN (shift only when cnt>0).
template<int MODE>
__global__ __launch_bounds__(256) void k_agg(
        const uint32_t* __restrict__ Src, int sstr,
        const int* __restrict__ offs, const int* __restrict__ counts,
        const int* __restrict__ ssrc,
        const float* __restrict__ bnscale, const float* __restrict__ bnshift,
        uint32_t* __restrict__ MbBase, int N){
    const int lane = threadIdx.x & 63;
    const int l15  = lane & 15;
    const int q    = lane >> 4;
    int node = blockIdx.x * 4 + (threadIdx.x >> 6);
    if (node >= N) return;
    int cnt = counts[node];
    if (cnt < 0) cnt = 0;
    int off = offs[node];
    const uint32_t* srcb = Src + l15 * 4;
    float a[8];
    #pragma unroll
    for (int i = 0; i < 8; ++i) a[i] = 0.f;

    int j = 0;
    for (; j + 8 <= cnt; j += 8){                     // 8 rows in flight (2 x 4 groups)
        int s0 = ssrc[off + j + q];
        int s1 = ssrc[off + j + 4 + q];
        s0 = (s0 < 0) ? 0 : ((s0 >= N) ? (N - 1) : s0);
        s1 = (s1 < 0) ? 0 : ((s1 >= N) ? (N - 1) : s1);
        uint4 v0 = *(const uint4*)(srcb + (size_t)s0 * sstr);
        uint4 v1 = *(const uint4*)(srcb + (size_t)s1 * sstr);
        a[0] += bflo(v0.x) + bflo(v1.x); a[1] += bfhi(v0.x) + bfhi(v1.x);
        a[2] += bflo(v0.y) + bflo(v1.y); a[3] += bfhi(v0.y) + bfhi(v1.y);
        a[4] += bflo(v0.z) + bflo(v1.z); a[5] += bfhi(v0.z) + bfhi(v1.z);
        a[6] += bflo(v0.w) + bflo(v1.w); a[7] += bfhi(v0.w) + bfhi(v1.w);
    }
    int rem = cnt - j;
    if (rem > 0){
        if (q < rem){
            int s0 = ssrc[off + j + q];
            s0 = (s0 < 0) ? 0 : ((s0 >= N) ? (N - 1) : s0);
            uint4 v0 = *(const uint4*)(srcb + (size_t)s0 * sstr);
            a[0] += bflo(v0.x); a[1] += bfhi(v0.x);
            a[2] += bflo(v0.y); a[3] += bfhi(v0.y);
            a[4] += bflo(v0.z); a[5] += bfhi(v0.z);
            a[6] += bflo(v0.w); a[7] += bfhi(v0.w);
        }
        if (rem > 4 && q < rem - 4){
            int s1 = ssrc[off + j + 4 + q];
            s1 = (s1 < 0) ? 0 : ((s1 >= N) ? (N - 1) : s1);
            uint4 v1 = *(const uint4*)(srcb + (size_t)s1 * sstr);
            a[0] += bflo(v1.x); a[1] += bfhi(v1.x);
            a[2] += bflo(v1.y); a[3] += bfhi(v1.y);
            a[4] += bflo(v1.z); a[5] += bfhi(v1.z);
            a[6] += bflo(v1.w); a[7] += bfhi(v1.w);
        }
    }

    // reduce across the 4 row-groups (lanes l15, l15+16, l15+32, l15+48)
    #pragma unroll
    for (int i = 0; i < 8; ++i){
        a[i] += __shfl_xor(a[i], 16, 64);
        a[i] += __shfl_xor(a[i], 32, 64);
    }
    float inv = 1.0f / fmaxf((float)cnt, 1.0f);
    #pragma unroll
    for (int i = 0; i < 8; ++i) a[i] *= inv;

    if (MODE == 1){
        if (cnt > 0){                                  // ref: zero-degree mean == 0
            int c0 = l15 * 8;
            float4 sc0 = *(const float4*)(bnscale + c0);
            float4 sc1 = *(const float4*)(bnscale + c0 + 4);
            float4 sh0 = *(const float4*)(bnshift + c0);
            float4 sh1 = *(const float4*)(bnshift + c0 + 4);
            a[0] = a[0] * sc0.x + sh0.x; a[1] = a[1] * sc0.y + sh0.y;
            a[2] = a[2] * sc0.z + sh0.z; a[3] = a[3] * sc0.w + sh0.w;
            a[4] = a[4] * sc1.x + sh1.x; a[5] = a[5] * sc1.y + sh1.y;
            a[6] = a[6] * sc1.z + sh1.z; a[7] = a[7] * sc1.w + sh1.w;
        } else {
            #pragma unroll
            for (int i = 0; i < 8; ++i) a[i] = 0.f;
        }
    }

    if (q == 0){
        uint4 o;
        o.x = packbf(a[0], a[1]); o.y = packbf(a[2], a[3]);
        o.z = packbf(a[4], a[5]); o.w = packbf(a[6], a[7]);
        *(uint4*)(MbBase + (size_t)node * 128 + 64 + l15 * 4) = o;
    }
}

// stage one quarter (32 KiB: 4 kt of one sel) of B into sB (8-wave version).
// LDS dest is wave-uniform base (+ lane*16 by HW); global src is per-lane.
__device__ __forceinline__ void stage4(const uint32_t* Wpk, uint32_t (*sB)[2048],
                                       int wid, int lane, int sel, int half){
    #pragma unroll
    for (int i = 0; i < 4; ++i){
        int ch = wid * 4 + i;                        // 32 chunks of 1 KiB
        int ktv = ch >> 3, part = ch & 7;
        __builtin_amdgcn_global_load_lds(
            Wpk + (size_t)(half * 4 + ktv) * 4096 + sel * 2048 + part * 256 + lane * 4,
            &sB[ktv][part * 256], 16, 0, 0);
    }
}

// ---------- MFMA dual-GEMM (K=256 = [mean|own]) + L2-normalize ----------
// 512 threads = 8 waves; each wave owns 16 rows (ONE m-tile), all 128 cols.
// (R7 structure: combined VGPR+AGPR ~110 < 128 -> launch_bounds(512,4) gives
// 2 blocks/CU without spills.)  B staged in FOUR 32 KiB quarters.
// A frag:  lane holds row (lane&15), k = 32*kt + 8*(lane>>4) + e  (contiguous 16B)
// B frag:  swizzled slot; gx = g ^ ((l15>>1)&3)   (conflict-free ds_read_b128)
// C/D:     col = lane&15, row = 4*(lane>>4) + reg   (m89-verified)
// MODE 0: own=Xbf (+Xlo correction on hi); out=relu(norm(.)); Hbf store + BN sums.
// MODE 1: own=Hbf (BN folded into Wpk/bias); out=norm(.); Emb f32 + preds.
template<int MODE>
__global__ __launch_bounds__(512, 4) void k_gemm(
        const uint32_t* Own,                 // MODE0: Xbf in Emb rows (stride 128); MODE1: Hbf (stride 64)
        const uint32_t* OwnLo,               // MODE0 only: Xlo (stride 64; aliases HbfOut)
        const uint32_t* Mb,                  // bf16 means at Emb rows' 2nd half
        const uint32_t* __restrict__ Wpk,    // packed+swizzled [kt][hi/lo][512 slots][8] u16
        const float* __restrict__ bias,      // [128] effective bias
        uint32_t* HbfOut,                    // MODE0 out (aliases OwnLo; alias-safe per-wave)
        float* Emb,                          // MODE1 out (aliases Mb rows; reads precede writes)
        float* __restrict__ bnsum, float* __restrict__ bnsumsq,             // MODE0
        const float* __restrict__ fcW, const float* __restrict__ fcb,       // MODE1
        float* __restrict__ preds, int N){
    __shared__ uint32_t __align__(16) sB[4][2048];   // 32 KiB; reused 4x; aliased by lsum/lsq at end
    const int lane = threadIdx.x & 63;
    const int wid  = threadIdx.x >> 6;               // 0..7
    const int l15  = lane & 15;
    const int g    = lane >> 4;
    const int gx4  = (g ^ ((l15 >> 1) & 3)) * 4;     // swizzled 16B sub-slot (u32 units)
    const int ostr = (MODE == 0) ? 128 : 64;
    const int wrow = blockIdx.x * 128 + wid * 16;    // this wave's 16-row m-tile

    stage4(Wpk, sB, wid, lane, 0, 0);                // quarter 1: hi, kt 0-3

    int ar0 = wrow + l15; if (ar0 >= N) ar0 = N - 1; // clamped dup rows: discarded

    const uint32_t* mp0 = Mb  + (size_t)ar0 * 128 + 64 + g * 4;
    const uint32_t* op0 = Own + (size_t)ar0 * ostr + g * 4;

    // hoist ALL A fragments into registers (independent loads, overlap staging)
    bf16x8 am[4], ao[4];
    #pragma unroll
    for (int kq = 0; kq < 4; ++kq){
        am[kq] = *(const bf16x8*)(mp0 + kq * 16);
        ao[kq] = *(const bf16x8*)(op0 + kq * 16);
    }
    bf16x8 xl[4];
    if (MODE == 0){
        #pragma unroll
        for (int kq = 0; kq < 4; ++kq)
            xl[kq] = *(const bf16x8*)(OwnLo + (size_t)ar0 * 64 + g * 4 + kq * 16);
    }

    f32x4 acc[8];
    const f32x4 zero = {0.f, 0.f, 0.f, 0.f};
    #pragma unroll
    for (int t = 0; t < 8; ++t) acc[t] = zero;

#define COMPUTE4(AM, ADD_XLO)                                                 \
    _Pragma("unroll")                                                         \
    for (int kk = 0; kk < 4; ++kk){                                           \
        _Pragma("unroll")                                                     \
        for (int t = 0; t < 8; ++t){                                          \
            bf16x8 bq = *(const bf16x8*)(&sB[kk][(t * 16 + l15) * 16 + gx4]); \
            acc[t] = MFMA(AM[kk], bq, acc[t]);                                \
            if (ADD_XLO) acc[t] = MFMA(xl[kk], bq, acc[t]);                   \
        }                                                                     \
    }

    __syncthreads();                                 // q1 staged + A-loads issued
    COMPUTE4(am, false);                             // hi, kt 0-3 (mean half)
    __syncthreads();
    stage4(Wpk, sB, wid, lane, 0, 1);                // quarter 2: hi, kt 4-7
    __syncthreads();
    COMPUTE4(ao, (MODE == 0));                       // hi, kt 4-7 (own half, +xlo)
    __syncthreads();
    stage4(Wpk, sB, wid, lane, 1, 0);                // quarter 3: lo, kt 0-3
    __syncthreads();
    COMPUTE4(am, false);                             // lo, kt 0-3
    __syncthreads();
    stage4(Wpk, sB, wid, lane, 1, 1);                // quarter 4: lo, kt 4-7
    __syncthreads();
    COMPUTE4(ao, false);                             // lo, kt 4-7
#undef COMPUTE4

    // ---- epilogue ----
    float bv[8];
    #pragma unroll
    for (int t = 0; t < 8; ++t) bv[t] = bias[t * 16 + l15];

    float fw[4]; float fb = 0.f;
    if (MODE == 1){
        #pragma unroll
        for (int t = 0; t < 4; ++t) fw[t] = fcW[t * 16 + l15];
        fb = fcb[0];
    }

    float pbs[8], pbq[8];
    #pragma unroll
    for (int t = 0; t < 8; ++t){ pbs[t] = 0.f; pbq[t] = 0.f; }

    #pragma unroll
    for (int j = 0; j < 4; ++j){
        int orow = wrow + 4 * g + j;
        bool valid = orow < N;
        float o[8]; float ss = 0.f;
        #pragma unroll
        for (int t = 0; t < 8; ++t){
            o[t] = acc[t][j] + bv[t];
            ss += o[t] * o[t];
        }
        ss += __shfl_xor(ss, 1, 64);
        ss += __shfl_xor(ss, 2, 64);
        ss += __shfl_xor(ss, 4, 64);
        ss += __shfl_xor(ss, 8, 64);
        float inv = 1.0f / fmaxf(sqrtf(ss), 1e-12f);
        if (MODE == 0){
            #pragma unroll
            for (int t = 0; t < 8; ++t){
                float v = fmaxf(o[t] * inv, 0.f);
                float pv = __shfl_xor(v, 1, 64);              // partner col (uniform exec)
                if (valid){
                    pbs[t] += v; pbq[t] += v * v;
                    if (!(lane & 1))
                        HbfOut[(size_t)orow * 64 + t * 8 + (l15 >> 1)] = packbf(v, pv);
                }
            }
        } else {
            float p = 0.f;
            #pragma unroll
            for (int t = 0; t < 8; ++t){
                float v = o[t] * inv;
                if (valid) Emb[(size_t)orow * 128 + t * 16 + l15] = v;
                if (t < 4) p += v * fw[t];
            }
            p += __shfl_xor(p, 1, 64);
            p += __shfl_xor(p, 2, 64);
            p += __shfl_xor(p, 4, 64);
            p += __shfl_xor(p, 8, 64);
            if (valid && l15 == 0) preds[orow] = p + fb;
        }
    }

    if (MODE == 0){
        float* lsum = (float*)&sB[0][0];             // sB dead after last compute
        float* lsq  = lsum + 128;
        #pragma unroll
        for (int t = 0; t < 8; ++t){
            pbs[t] += __shfl_xor(pbs[t], 16, 64);
            pbs[t] += __shfl_xor(pbs[t], 32, 64);
            pbq[t] += __shfl_xor(pbq[t], 16, 64);
            pbq[t] += __shfl_xor(pbq[t], 32, 64);
        }
        __syncthreads();                             // all waves done reading sB
        if (threadIdx.x < 128){ lsum[threadIdx.x] = 0.f; lsq[threadIdx.x] = 0.f; }
        __syncthreads();
        if (lane < 16){
            #pragma unroll
            for (int t = 0; t < 8; ++t){
                atomicAdd(&lsum[t * 16 + lane], pbs[t]);
                atomicAdd(&lsq [t * 16 + lane], pbq[t]);
            }
        }
        __syncthreads();
        if (threadIdx.x < 128){
            atomicAdd(&bnsum[threadIdx.x],   lsum[threadIdx.x]);
            atomicAdd(&bnsumsq[threadIdx.x], lsq[threadIdx.x]);
        }
    }
}

// ---------- fused BN finalize + layer-2 weight pack ----------
// blocks 0..127: pack W2 (scale for k>=128 computed locally from bnsum/bnsumsq).
// block 128:     bnscale/bnshift arrays (for k_agg<1>) + bias2 = b2 + shift @ W2r.
__global__ __launch_bounds__(256) void k_bnwprep2(
        const float* __restrict__ bnsum, const float* __restrict__ bnsumsq,
        const float* __restrict__ gamma, const float* __restrict__ beta,
        const float* __restrict__ W2l, const float* __restrict__ W2r,
        const float* __restrict__ b2,
        uint16_t* __restrict__ Wpk2,
        float* __restrict__ bnscale, float* __restrict__ bnshift,
        float* __restrict__ bias2, int N){
    const float invN = 1.0f / (float)N;
    int bid = blockIdx.x, t = threadIdx.x;
    if (bid < 128){
        int idx = bid * 256 + t;
        int k = idx & 255, c = idx >> 8;
        float v;
        if (k < 128){
            v = W2l[k * 128 + c];
        } else {
            int ch = k - 128;
            float mu  = bnsum[ch] * invN;
            float var = fmaxf(bnsumsq[ch] * invN - mu * mu, 0.f);
            float sc  = gamma[ch] * (1.0f / sqrtf(var + 1e-5f));
            v = W2r[ch * 128 + c] * sc;
        }
        wpack_one(Wpk2, idx, v);
    } else {
        __shared__ float sh_l[128];
        if (t < 128){
            float mu  = bnsum[t] * invN;
            float var = fmaxf(bnsumsq[t] * invN - mu * mu, 0.f);
            float istd = 1.0f / sqrtf(var + 1e-5f);
            float sc = gamma[t] * istd;
            float sf = beta[t] - mu * sc;
            bnscale[t] = sc; bnshift[t] = sf; sh_l[t] = sf;
        }
        __syncthreads();
        if (t < 128){
            float acc = b2[t];
            for (int k2 = 0; k2 < 128; ++k2) acc += sh_l[k2] * W2r[k2 * 128 + t];
            bias2[t] = acc;
        }
    }
}

__global__ void k_sent(float* __restrict__ preds, int N, float val){
    int i = blockIdx.x * 256 + threadIdx.x;
    if (i < N) preds[i] = val;
}

// ---------- launch ----------
extern "C" void kernel_launch(void* const* d_in, const int* in_sizes, int n_in,
                              void* d_out, int out_size, void* d_ws, size_t ws_size,
                              hipStream_t stream){
    const int N = in_sizes[0] / 128;
    const int E = in_sizes[1] / 2;

    const float* x    = (const float*)d_in[0];
    const int*   ei   = (const int*)d_in[1];
    const int*   src  = ei;
    const int*   dst  = ei + E;
    const float* W1l  = (const float*)d_in[2];
    const float* b1   = (const float*)d_in[3];
    const float* W1r  = (const float*)d_in[4];
    const float* gam  = (const float*)d_in[5];
    const float* bet  = (const float*)d_in[6];
    const float* W2l  = (const float*)d_in[7];
    const float* b2   = (const float*)d_in[8];
    const float* W2r  = (const float*)d_in[9];
    const float* fcW  = (const float*)d_in[10];
    const float* fcb  = (const float*)d_in[11];

    float* preds = (float*)d_out;                 // f32 [N]
    float* Emb   = preds + N;                     // f32 [N,128]
    uint32_t* EmbU = (uint32_t*)Emb;              // Xbf (1st half) + Mb (2nd half) scratch

    char* w = (char*)d_ws;
    auto carve = [&](size_t bytes){ char* p = w; w += (bytes + 255) & ~(size_t)255; return p; };
    int*   counts  = (int*)  carve((size_t)N * 8);   // counts[N] + cursor[N], one memset
    int*   cursor  = counts + N;
    int*   offs    = (int*)  carve((size_t)N * 4);
    int*   bsums   = (int*)  carve(256 * 4);
    float* bnsum   = (float*)carve(128 * 4);      // contiguous with bnsumsq (zeroed in k_prep)
    float* bnsumsq = (float*)carve(128 * 4);
    float* bnscale = (float*)carve(128 * 4);
    float* bnshift = (float*)carve(128 * 4);
    float* bias2   = (float*)carve(128 * 4);
    int*   ssrc    = (int*)  carve((size_t)E * 4);
    uint32_t* HbfXlo = (uint32_t*)carve((size_t)N * 256);  // Xlo then Hbf (overlay, alias-safe)
    uint16_t* Wpk1 = (uint16_t*)carve(131072);    // packed+swizzled [kt][hi/lo][512][8]
    uint16_t* Wpk2 = (uint16_t*)carve(131072);
    size_t need = (size_t)(w - (char*)d_ws);
    if (ws_size < need){
        float val = 1024.f + 4.f * (float)((ws_size >> 20) > 255 ? 255 : (ws_size >> 20));
        k_sent<<<(N + 255) / 256, 256, 0, stream>>>(preds, N, val);
        return;
    }

    hipMemsetAsync(counts, 0, (size_t)N * 8, stream);

    const int eb = (E + 255) / 256;
    const int NB = (N + 2047) / 2048;
    const int ab = (N + 3) / 4;
    const int gb = (N + 127) / 128;
    const int xb = (N * 32 + 255) / 256;

    // fused prep: wprep1 | x2bf | deg (+ bnsum zero)
    k_prep <<<128 + xb + eb, 256, 0, stream>>>(x, EmbU, HbfXlo, dst, counts,
                                               W1l, W1r, Wpk1, bnsum, N, E, xb);
    k_scan1<<<NB, 256, 0, stream>>>(counts, bsums, N);
    k_scan3<<<NB, 256, 0, stream>>>(counts, bsums, offs, N);
    k_fill <<<eb, 256, 0, stream>>>(src, dst, offs, cursor, ssrc, E);

    // layer 1
    k_agg<0> <<<ab, 256, 0, stream>>>(EmbU, 128, offs, counts, ssrc,
                                      nullptr, nullptr, EmbU, N);
    k_gemm<0><<<gb, 512, 0, stream>>>(EmbU, HbfXlo, EmbU, (const uint32_t*)Wpk1, b1,
                                      HbfXlo, nullptr, bnsum, bnsumsq,
                                      nullptr, nullptr, nullptr, N);
    // fused BN finalize + layer-2 pack
    k_bnwprep2<<<129, 256, 0, stream>>>(bnsum, bnsumsq, gam, bet, W2l, W2r, b2,
                                        Wpk2, bnscale, bnshift, bias2, N);

    // layer 2
    k_agg<1> <<<ab, 256, 0, stream>>>(HbfXlo, 64, offs, counts, ssrc,
                                      bnscale, bnshift, EmbU, N);
    k_gemm<1><<<gb, 512, 0, stream>>>(HbfXlo, nullptr, EmbU, (const uint32_t*)Wpk2, bias2,
                                      nullptr, Emb, nullptr, nullptr,
                                      fcW, fcb, preds, N);
}

// Round 10
// 331.162 us; speedup vs baseline: 1.3006x; 1.0264x over previous
//
#include <hip/hip_runtime.h>
#include <hip/hip_bf16.h>
#include <stdint.h>

typedef __attribute__((ext_vector_type(8))) __bf16 bf16x8;
typedef __attribute__((ext_vector_type(4))) float  f32x4;

// ---------- bf16 helpers (bf16 pairs packed in uint32, little-endian) ----------
__device__ __forceinline__ float bflo(uint32_t p){ return __uint_as_float(p << 16); }
__device__ __forceinline__ float bfhi(uint32_t p){ return __uint_as_float(p & 0xffff0000u); }
__device__ __forceinline__ uint16_t f2bf(float f){
    uint32_t u = __float_as_uint(f);
    uint32_t r = (u + 0x7fffu + ((u >> 16) & 1u)) >> 16;   // RNE
    return (uint16_t)r;
}
__device__ __forceinline__ uint32_t packbf(float a, float b){
    return (uint32_t)f2bf(a) | ((uint32_t)f2bf(b) << 16);
}
__device__ __forceinline__ f32x4 MFMA(bf16x8 a, bf16x8 b, f32x4 c){
    return __builtin_amdgcn_mfma_f32_16x16x32_bf16(a, b, c, 0, 0, 0);
}

// Mean buffer lives in the SECOND HALF of each f32 Emb row (u32 units);
// Xbf (layer-1 bf16 input) lives in the FIRST HALF.

// ---------- weight pack helper (shared by k_prep / k_bnwprep2) ----------
// Wpk u16 layout: [kt(8)][sel(2: hi,lo)][slot(512)][e(8)]
//   slot(c,g) = 4*c + (g ^ ((c>>1)&3))   (bank swizzle for conflict-free ds_read_b128)
__device__ __forceinline__ void wpack_one(uint16_t* __restrict__ Wpk, int idx, float v){
    int c = idx >> 8, k = idx & 255;
    uint16_t h = f2bf(v);
    float r = v - __uint_as_float((uint32_t)h << 16);
    int kt = k >> 5, kk = k & 31;
    int g = kk >> 3, e = kk & 7;
    int slot = (c << 2) | (g ^ ((c >> 1) & 3));
    size_t base = (size_t)kt * 8192 + (size_t)slot * 8 + e;
    Wpk[base]        = h;
    Wpk[base + 4096] = f2bf(r);
}

// ---------- fused prep: wprep1 | x2bf (grid-stride) | deg (grid-stride) ----------
// Fixed 2176-block grid (Guideline 11: many-small-block launches pay CP dispatch
// rate; grid-stride instead).  blocks 0..127: W1 pack + bnsum zero.
// blocks 128..1151: x2bf stride loop.  blocks 1152..2175: deg stride loop.
__global__ __launch_bounds__(256) void k_prep(
        const float* __restrict__ X, uint32_t* __restrict__ XbfE, uint32_t* __restrict__ Xlo,
        const int* __restrict__ dst, int* __restrict__ counts,
        const float* __restrict__ W1l, const float* __restrict__ W1r,
        uint16_t* __restrict__ Wpk1, float* __restrict__ bnsum,
        int N, int E){
    int bid = blockIdx.x, tid = threadIdx.x;
    if (bid < 128){
        if (bid == 0) bnsum[tid] = 0.f;              // bnsum[128]+bnsumsq[128] contiguous
        int idx = bid * 256 + tid;                   // [0, 32768) = c*256 + k
        int k = idx & 255, c = idx >> 8;
        float v = (k < 128) ? W1l[k * 128 + c] : W1r[(k - 128) * 128 + c];
        wpack_one(Wpk1, idx, v);
    } else if (bid < 128 + 1024){
        const int stride = 1024 * 256;
        for (int i = (bid - 128) * 256 + tid; i < N * 32; i += stride){
            int row = i >> 5, l = i & 31;
            float4 v = *(const float4*)(X + (size_t)i * 4);
            uint16_t h0 = f2bf(v.x), h1 = f2bf(v.y), h2 = f2bf(v.z), h3 = f2bf(v.w);
            float r0 = v.x - __uint_as_float((uint32_t)h0 << 16);
            float r1 = v.y - __uint_as_float((uint32_t)h1 << 16);
            float r2 = v.z - __uint_as_float((uint32_t)h2 << 16);
            float r3 = v.w - __uint_as_float((uint32_t)h3 << 16);
            uint2 hi; hi.x = (uint32_t)h0 | ((uint32_t)h1 << 16);
            hi.y = (uint32_t)h2 | ((uint32_t)h3 << 16);
            uint2 lo; lo.x = packbf(r0, r1); lo.y = packbf(r2, r3);
            *(uint2*)(XbfE + (size_t)row * 128 + l * 2) = hi;
            *(uint2*)(Xlo  + (size_t)row * 64  + l * 2) = lo;
        }
    } else {
        const int stride = 1024 * 256;
        for (int e = (bid - 1152) * 256 + tid; e < E; e += stride)
            atomicAdd(&counts[dst[e]], 1);
    }
}

// ---------- CSR scans ----------
__global__ void k_scan1(const int* __restrict__ counts, int* __restrict__ bsums, int N){
    __shared__ int lds[256];
    int t = threadIdx.x;
    int base = blockIdx.x * 2048 + t * 8;
    int s = 0;
    #pragma unroll
    for (int i = 0; i < 8; ++i){ int idx = base + i; s += (idx < N) ? counts[idx] : 0; }
    lds[t] = s; __syncthreads();
    for (int off = 128; off > 0; off >>= 1){
        if (t < off) lds[t] += lds[t + off];
        __syncthreads();
    }
    if (t == 0) bsums[blockIdx.x] = lds[0];
}

// scan3 computes its own prefix of bsums (one wave, NB<=64) — no k_scan2.
__global__ void k_scan3(const int* __restrict__ counts, const int* __restrict__ bsums,
                        int* __restrict__ offs, int N){
    __shared__ int lds[256];
    __shared__ int base_s;
    int t = threadIdx.x;
    if (t < 64){
        int s2 = 0;
        for (int i = t; i < (int)blockIdx.x; i += 64) s2 += bsums[i];
        #pragma unroll
        for (int m = 32; m >= 1; m >>= 1) s2 += __shfl_xor(s2, m, 64);
        if (t == 0) base_s = s2;
    }
    int base = blockIdx.x * 2048 + t * 8;
    int local[8];
    int s = 0;
    #pragma unroll
    for (int i = 0; i < 8; ++i){
        int idx = base + i;
        int v = (idx < N) ? counts[idx] : 0;
        local[i] = v; s += v;
    }
    lds[t] = s; __syncthreads();                     // also publishes base_s
    for (int off = 1; off < 256; off <<= 1){
        int v = (t >= off) ? lds[t - off] : 0;
        __syncthreads();
        lds[t] += v;
        __syncthreads();
    }
    int run = base_s + (lds[t] - s);
    #pragma unroll
    for (int i = 0; i < 8; ++i){
        int idx = base + i;
        if (idx < N){ offs[idx] = run; run += local[i]; }
    }
}

__global__ void k_fill(const int* __restrict__ src, const int* __restrict__ dst,
                       const int* __restrict__ offs, int* __restrict__ cursor,
                       int* __restrict__ ssrc, int E){
    const int stride = gridDim.x * 256;
    for (int e = blockIdx.x * 256 + threadIdx.x; e < E; e += stride){
        int d = dst[e];
        int p = atomicAdd(&cursor[d], 1);
        ssrc[offs[d] + p] = src[e];
    }
}

// ---------- neighbor mean: grid-stride, one wave per node per iteration ----------
// 2048 blocks x 4 waves = 8192 waves (32/CU — full residency, ~12 nodes/wave)
// instead of 25k one-shot blocks (CP dispatch-rate bound).  Per-node math and
// summation order identical to the one-node-per-wave version.
template<int MODE>
__global__ __launch_bounds__(256) void k_agg(
        const uint32_t* __restrict__ Src, int sstr,
        const int* __restrict__ offs, const int* __restrict__ counts,
        const int* __restrict__ ssrc,
        const float* __restrict__ bnscale, const float* __restrict__ bnshift,
        uint32_t* __restrict__ MbBase, int N){
    const int lane = threadIdx.x & 63;
    const int l15  = lane & 15;
    const int q    = lane >> 4;
    const int nwaves = gridDim.x * 4;
    const uint32_t* srcb = Src + l15 * 4;

    float sc[8], sh[8];                              // BN fold constants (node-invariant)
    if (MODE == 1){
        int c0 = l15 * 8;
        float4 s0 = *(const float4*)(bnscale + c0);
        float4 s1 = *(const float4*)(bnscale + c0 + 4);
        float4 h0 = *(const float4*)(bnshift + c0);
        float4 h1 = *(const float4*)(bnshift + c0 + 4);
        sc[0]=s0.x; sc[1]=s0.y; sc[2]=s0.z; sc[3]=s0.w;
        sc[4]=s1.x; sc[5]=s1.y; sc[6]=s1.z; sc[7]=s1.w;
        sh[0]=h0.x; sh[1]=h0.y; sh[2]=h0.z; sh[3]=h0.w;
        sh[4]=h1.x; sh[5]=h1.y; sh[6]=h1.z; sh[7]=h1.w;
    }

    for (int node = blockIdx.x * 4 + (threadIdx.x >> 6); node < N; node += nwaves){
        int cnt = counts[node];
        if (cnt < 0) cnt = 0;
        int off = offs[node];
        float a[8];
        #pragma unroll
        for (int i = 0; i < 8; ++i) a[i] = 0.f;

        int j = 0;
        for (; j + 8 <= cnt; j += 8){                 // 8 rows in flight (2 x 4 groups)
            int s0 = ssrc[off + j + q];
            int s1 = ssrc[off + j + 4 + q];
            s0 = (s0 < 0) ? 0 : ((s0 >= N) ? (N - 1) : s0);
            s1 = (s1 < 0) ? 0 : ((s1 >= N) ? (N - 1) : s1);
            uint4 v0 = *(const uint4*)(srcb + (size_t)s0 * sstr);
            uint4 v1 = *(const uint4*)(srcb + (size_t)s1 * sstr);
            a[0] += bflo(v0.x) + bflo(v1.x); a[1] += bfhi(v0.x) + bfhi(v1.x);
            a[2] += bflo(v0.y) + bflo(v1.y); a[3] += bfhi(v0.y) + bfhi(v1.y);
            a[4] += bflo(v0.z) + bflo(v1.z); a[5] += bfhi(v0.z) + bfhi(v1.z);
            a[6] += bflo(v0.w) + bflo(v1.w); a[7] += bfhi(v0.w) + bfhi(v1.w);
        }
        int rem = cnt - j;
        if (rem > 0){
            if (q < rem){
                int s0 = ssrc[off + j + q];
                s0 = (s0 < 0) ? 0 : ((s0 >= N) ? (N - 1) : s0);
                uint4 v0 = *(const uint4*)(srcb + (size_t)s0 * sstr);
                a[0] += bflo(v0.x); a[1] += bfhi(v0.x);
                a[2] += bflo(v0.y); a[3] += bfhi(v0.y);
                a[4] += bflo(v0.z); a[5] += bfhi(v0.z);
                a[6] += bflo(v0.w); a[7] += bfhi(v0.w);
            }
            if (rem > 4 && q < rem - 4){
                int s1 = ssrc[off + j + 4 + q];
                s1 = (s1 < 0) ? 0 : ((s1 >= N) ? (N - 1) : s1);
                uint4 v1 = *(const uint4*)(srcb + (size_t)s1 * sstr);
                a[0] += bflo(v1.x); a[1] += bfhi(v1.x);
                a[2] += bflo(v1.y); a[3] += bfhi(v1.y);
                a[4] += bflo(v1.z); a[5] += bfhi(v1.z);
                a[6] += bflo(v1.w); a[7] += bfhi(v1.w);
            }
        }

        // reduce across the 4 row-groups (lanes l15, l15+16, l15+32, l15+48)
        #pragma unroll
        for (int i = 0; i < 8; ++i){
            a[i] += __shfl_xor(a[i], 16, 64);
            a[i] += __shfl_xor(a[i], 32, 64);
        }
        float inv = 1.0f / fmaxf((float)cnt, 1.0f);
        #pragma unroll
        for (int i = 0; i < 8; ++i) a[i] *= inv;

        if (MODE == 1){
            if (cnt > 0){                             // ref: zero-degree mean == 0
                #pragma unroll
                for (int i = 0; i < 8; ++i) a[i] = a[i] * sc[i] + sh[i];
            } else {
                #pragma unroll
                for (int i = 0; i < 8; ++i) a[i] = 0.f;
            }
        }

        if (q == 0){
            uint4 o;
            o.x = packbf(a[0], a[1]); o.y = packbf(a[2], a[3]);
            o.z = packbf(a[4], a[5]); o.w = packbf(a[6], a[7]);
            *(uint4*)(MbBase + (size_t)node * 128 + 64 + l15 * 4) = o;
        }
    }
}

// stage one quarter (32 KiB: 4 kt of one sel) of B into sB (8-wave version).
// LDS dest is wave-uniform base (+ lane*16 by HW); global src is per-lane.
__device__ __forceinline__ void stage4(const uint32_t* Wpk, uint32_t (*sB)[2048],
                                       int wid, int lane, int sel, int half){
    #pragma unroll
    for (int i = 0; i < 4; ++i){
        int ch = wid * 4 + i;                        // 32 chunks of 1 KiB
        int ktv = ch >> 3, part = ch & 7;
        __builtin_amdgcn_global_load_lds(
            Wpk + (size_t)(half * 4 + ktv) * 4096 + sel * 2048 + part * 256 + lane * 4,
            &sB[ktv][part * 256], 16, 0, 0);
    }
}

// ---------- MFMA dual-GEMM (K=256 = [mean|own]) + L2-normalize ----------
// 512 threads = 8 waves; each wave owns 16 rows (ONE m-tile), all 128 cols.
// (R7 structure: combined VGPR+AGPR ~90 < 128 -> launch_bounds(512,4) gives
// 2 blocks/CU without spills.)  B staged in FOUR 32 KiB quarters.
// A frag:  lane holds row (lane&15), k = 32*kt + 8*(lane>>4) + e  (contiguous 16B)
// B frag:  swizzled slot; gx = g ^ ((l15>>1)&3)   (conflict-free ds_read_b128)
// C/D:     col = lane&15, row = 4*(lane>>4) + reg   (m89-verified)
// MODE 0: own=Xbf (+Xlo correction on hi); out=relu(norm(.)); Hbf store + BN sums.
// MODE 1: own=Hbf (BN folded into Wpk/bias); out=norm(.); Emb f32 + preds.
template<int MODE>
__global__ __launch_bounds__(512, 4) void k_gemm(
        const uint32_t* Own,                 // MODE0: Xbf in Emb rows (stride 128); MODE1: Hbf (stride 64)
        const uint32_t* OwnLo,               // MODE0 only: Xlo (stride 64; aliases HbfOut)
        const uint32_t* Mb,                  // bf16 means at Emb rows' 2nd half
        const uint32_t* __restrict__ Wpk,    // packed+swizzled [kt][hi/lo][512 slots][8] u16
        const float* __restrict__ bias,      // [128] effective bias
        uint32_t* HbfOut,                    // MODE0 out (aliases OwnLo; alias-safe per-wave)
        float* Emb,                          // MODE1 out (aliases Mb rows; reads precede writes)
        float* __restrict__ bnsum, float* __restrict__ bnsumsq,             // MODE0
        const float* __restrict__ fcW, const float* __restrict__ fcb,       // MODE1
        float* __restrict__ preds, int N){
    __shared__ uint32_t __align__(16) sB[4][2048];   // 32 KiB; reused 4x; aliased by lsum/lsq at end
    const int lane = threadIdx.x & 63;
    const int wid  = threadIdx.x >> 6;               // 0..7
    const int l15  = lane & 15;
    const int g    = lane >> 4;
    const int gx4  = (g ^ ((l15 >> 1) & 3)) * 4;     // swizzled 16B sub-slot (u32 units)
    const int ostr = (MODE == 0) ? 128 : 64;
    const int wrow = blockIdx.x * 128 + wid * 16;    // this wave's 16-row m-tile

    stage4(Wpk, sB, wid, lane, 0, 0);                // quarter 1: hi, kt 0-3

    int ar0 = wrow + l15; if (ar0 >= N) ar0 = N - 1; // clamped dup rows: discarded

    const uint32_t* mp0 = Mb  + (size_t)ar0 * 128 + 64 + g * 4;
    const uint32_t* op0 = Own + (size_t)ar0 * ostr + g * 4;

    // hoist ALL A fragments into registers (independent loads, overlap staging)
    bf16x8 am[4], ao[4];
    #pragma unroll
    for (int kq = 0; kq < 4; ++kq){
        am[kq] = *(const bf16x8*)(mp0 + kq * 16);
        ao[kq] = *(const bf16x8*)(op0 + kq * 16);
    }
    bf16x8 xl[4];
    if (MODE == 0){
        #pragma unroll
        for (int kq = 0; kq < 4; ++kq)
            xl[kq] = *(const bf16x8*)(OwnLo + (size_t)ar0 * 64 + g * 4 + kq * 16);
    }

    f32x4 acc[8];
    const f32x4 zero = {0.f, 0.f, 0.f, 0.f};
    #pragma unroll
    for (int t = 0; t < 8; ++t) acc[t] = zero;

#define COMPUTE4(AM, ADD_XLO)                                                 \
    _Pragma("unroll")                                                         \
    for (int kk = 0; kk < 4; ++kk){                                           \
        _Pragma("unroll")                                                     \
        for (int t = 0; t < 8; ++t){                                          \
            bf16x8 bq = *(const bf16x8*)(&sB[kk][(t * 16 + l15) * 16 + gx4]); \
            acc[t] = MFMA(AM[kk], bq, acc[t]);                                \
            if (ADD_XLO) acc[t] = MFMA(xl[kk], bq, acc[t]);                   \
        }                                                                     \
    }

    __syncthreads();                                 // q1 staged + A-loads issued
    COMPUTE4(am, false);                             // hi, kt 0-3 (mean half)
    __syncthreads();
    stage4(Wpk, sB, wid, lane, 0, 1);                // quarter 2: hi, kt 4-7
    __syncthreads();
    COMPUTE4(ao, (MODE == 0));                       // hi, kt 4-7 (own half, +xlo)
    __syncthreads();
    stage4(Wpk, sB, wid, lane, 1, 0);                // quarter 3: lo, kt 0-3
    __syncthreads();
    COMPUTE4(am, false);                             // lo, kt 0-3
    __syncthreads();
    stage4(Wpk, sB, wid, lane, 1, 1);                // quarter 4: lo, kt 4-7
    __syncthreads();
    COMPUTE4(ao, false);                             // lo, kt 4-7
#undef COMPUTE4

    // ---- epilogue ----
    float bv[8];
    #pragma unroll
    for (int t = 0; t < 8; ++t) bv[t] = bias[t * 16 + l15];

    float fw[4]; float fb = 0.f;
    if (MODE == 1){
        #pragma unroll
        for (int t = 0; t < 4; ++t) fw[t] = fcW[t * 16 + l15];
        fb = fcb[0];
    }

    float pbs[8], pbq[8];
    #pragma unroll
    for (int t = 0; t < 8; ++t){ pbs[t] = 0.f; pbq[t] = 0.f; }

    #pragma unroll
    for (int j = 0; j < 4; ++j){
        int orow = wrow + 4 * g + j;
        bool valid = orow < N;
        float o[8]; float ss = 0.f;
        #pragma unroll
        for (int t = 0; t < 8; ++t){
            o[t] = acc[t][j] + bv[t];
            ss += o[t] * o[t];
        }
        ss += __shfl_xor(ss, 1, 64);
        ss += __shfl_xor(ss, 2, 64);
        ss += __shfl_xor(ss, 4, 64);
        ss += __shfl_xor(ss, 8, 64);
        float inv = 1.0f / fmaxf(sqrtf(ss), 1e-12f);
        if (MODE == 0){
            #pragma unroll
            for (int t = 0; t < 8; ++t){
                float v = fmaxf(o[t] * inv, 0.f);
                float pv = __shfl_xor(v, 1, 64);              // partner col (uniform exec)
                if (valid){
                    pbs[t] += v; pbq[t] += v * v;
                    if (!(lane & 1))
                        HbfOut[(size_t)orow * 64 + t * 8 + (l15 >> 1)] = packbf(v, pv);
                }
            }
        } else {
            float p = 0.f;
            #pragma unroll
            for (int t = 0; t < 8; ++t){
                float v = o[t] * inv;
                if (valid) Emb[(size_t)orow * 128 + t * 16 + l15] = v;
                if (t < 4) p += v * fw[t];
            }
            p += __shfl_xor(p, 1, 64);
            p += __shfl_xor(p, 2, 64);
            p += __shfl_xor(p, 4, 64);
            p += __shfl_xor(p, 8, 64);
            if (valid && l15 == 0) preds[orow] = p + fb;
        }
    }

    if (MODE == 0){
        float* lsum = (float*)&sB[0][0];             // sB dead after last compute
        float* lsq  = lsum + 128;
        #pragma unroll
        for (int t = 0; t < 8; ++t){
            pbs[t] += __shfl_xor(pbs[t], 16, 64);
            pbs[t] += __shfl_xor(pbs[t], 32, 64);
            pbq[t] += __shfl_xor(pbq[t], 16, 64);
            pbq[t] += __shfl_xor(pbq[t], 32, 64);
        }
        __syncthreads();                             // all waves done reading sB
        if (threadIdx.x < 128){ lsum[threadIdx.x] = 0.f; lsq[threadIdx.x] = 0.f; }
        __syncthreads();
        if (lane < 16){
            #pragma unroll
            for (int t = 0; t < 8; ++t){
                atomicAdd(&lsum[t * 16 + lane], pbs[t]);
                atomicAdd(&lsq [t * 16 + lane], pbq[t]);
            }
        }
        __syncthreads();
        if (threadIdx.x < 128){
            atomicAdd(&bnsum[threadIdx.x],   lsum[threadIdx.x]);
            atomicAdd(&bnsumsq[threadIdx.x], lsq[threadIdx.x]);
        }
    }
}

// ---------- fused BN finalize + layer-2 weight pack ----------
// blocks 0..127: pack W2 (scale for k>=128 computed locally from bnsum/bnsumsq).
// block 128:     bnscale/bnshift arrays (for k_agg<1>) + bias2 = b2 + shift @ W2r.
__global__ __launch_bounds__(256) void k_bnwprep2(
        const float* __restrict__ bnsum, const float* __restrict__ bnsumsq,
        const float* __restrict__ gamma, const float* __restrict__ beta,
        const float* __restrict__ W2l, const float* __restrict__ W2r,
        const float* __restrict__ b2,
        uint16_t* __restrict__ Wpk2,
        float* __restrict__ bnscale, float* __restrict__ bnshift,
        float* __restrict__ bias2, int N){
    const float invN = 1.0f / (float)N;
    int bid = blockIdx.x, t = threadIdx.x;
    if (bid < 128){
        int idx = bid * 256 + t;
        int k = idx & 255, c = idx >> 8;
        float v;
        if (k < 128){
            v = W2l[k * 128 + c];
        } else {
            int ch = k - 128;
            float mu  = bnsum[ch] * invN;
            float var = fmaxf(bnsumsq[ch] * invN - mu * mu, 0.f);
            float sc  = gamma[ch] * (1.0f / sqrtf(var + 1e-5f));
            v = W2r[ch * 128 + c] * sc;
        }
        wpack_one(Wpk2, idx, v);
    } else {
        __shared__ float sh_l[128];
        if (t < 128){
            float mu  = bnsum[t] * invN;
            float var = fmaxf(bnsumsq[t] * invN - mu * mu, 0.f);
            float istd = 1.0f / sqrtf(var + 1e-5f);
            float sc = gamma[t] * istd;
            float sf = beta[t] - mu * sc;
            bnscale[t] = sc; bnshift[t] = sf; sh_l[t] = sf;
        }
        __syncthreads();
        if (t < 128){
            float acc = b2[t];
            for (int k2 = 0; k2 < 128; ++k2) acc += sh_l[k2] * W2r[k2 * 128 + t];
            bias2[t] = acc;
        }
    }
}

__global__ void k_sent(float* __restrict__ preds, int N, float val){
    int i = blockIdx.x * 256 + threadIdx.x;
    if (i < N) preds[i] = val;
}

// ---------- launch ----------
extern "C" void kernel_launch(void* const* d_in, const int* in_sizes, int n_in,
                              void* d_out, int out_size, void* d_ws, size_t ws_size,
                              hipStream_t stream){
    const int N = in_sizes[0] / 128;
    const int E = in_sizes[1] / 2;

    const float* x    = (const float*)d_in[0];
    const int*   ei   = (const int*)d_in[1];
    const int*   src  = ei;
    const int*   dst  = ei + E;
    const float* W1l  = (const float*)d_in[2];
    const float* b1   = (const float*)d_in[3];
    const float* W1r  = (const float*)d_in[4];
    const float* gam  = (const float*)d_in[5];
    const float* bet  = (const float*)d_in[6];
    const float* W2l  = (const float*)d_in[7];
    const float* b2   = (const float*)d_in[8];
    const float* W2r  = (const float*)d_in[9];
    const float* fcW  = (const float*)d_in[10];
    const float* fcb  = (const float*)d_in[11];

    float* preds = (float*)d_out;                 // f32 [N]
    float* Emb   = preds + N;                     // f32 [N,128]
    uint32_t* EmbU = (uint32_t*)Emb;              // Xbf (1st half) + Mb (2nd half) scratch

    char* w = (char*)d_ws;
    auto carve = [&](size_t bytes){ char* p = w; w += (bytes + 255) & ~(size_t)255; return p; };
    int*   counts  = (int*)  carve((size_t)N * 8);   // counts[N] + cursor[N], one memset
    int*   cursor  = counts + N;
    int*   offs    = (int*)  carve((size_t)N * 4);
    int*   bsums   = (int*)  carve(256 * 4);
    float* bnsum   = (float*)carve(128 * 4);      // contiguous with bnsumsq (zeroed in k_prep)
    float* bnsumsq = (float*)carve(128 * 4);
    float* bnscale = (float*)carve(128 * 4);
    float* bnshift = (float*)carve(128 * 4);
    float* bias2   = (float*)carve(128 * 4);
    int*   ssrc    = (int*)  carve((size_t)E * 4);
    uint32_t* HbfXlo = (uint32_t*)carve((size_t)N * 256);  // Xlo then Hbf (overlay, alias-safe)
    uint16_t* Wpk1 = (uint16_t*)carve(131072);    // packed+swizzled [kt][hi/lo][512][8]
    uint16_t* Wpk2 = (uint16_t*)carve(131072);
    size_t need = (size_t)(w - (char*)d_ws);
    if (ws_size < need){
        float val = 1024.f + 4.f * (float)((ws_size >> 20) > 255 ? 255 : (ws_size >> 20));
        k_sent<<<(N + 255) / 256, 256, 0, stream>>>(preds, N, val);
        return;
    }

    hipMemsetAsync(counts, 0, (size_t)N * 8, stream);

    const int NB = (N + 2047) / 2048;
    const int gb = (N + 127) / 128;

    // fused prep: wprep1 | x2bf | deg (grid-stride sections, fixed 2176 blocks)
    k_prep <<<2176, 256, 0, stream>>>(x, EmbU, HbfXlo, dst, counts,
                                      W1l, W1r, Wpk1, bnsum, N, E);
    k_scan1<<<NB, 256, 0, stream>>>(counts, bsums, N);
    k_scan3<<<NB, 256, 0, stream>>>(counts, bsums, offs, N);
    k_fill <<<2048, 256, 0, stream>>>(src, dst, offs, cursor, ssrc, E);

    // layer 1
    k_agg<0> <<<2048, 256, 0, stream>>>(EmbU, 128, offs, counts, ssrc,
                                        nullptr, nullptr, EmbU, N);
    k_gemm<0><<<gb, 512, 0, stream>>>(EmbU, HbfXlo, EmbU, (const uint32_t*)Wpk1, b1,
                                      HbfXlo, nullptr, bnsum, bnsumsq,
                                      nullptr, nullptr, nullptr, N);
    // fused BN finalize + layer-2 pack
    k_bnwprep2<<<129, 256, 0, stream>>>(bnsum, bnsumsq, gam, bet, W2l, W2r, b2,
                                        Wpk2, bnscale, bnshift, bias2, N);

    // layer 2
    k_agg<1> <<<2048, 256, 0, stream>>>(HbfXlo, 64, offs, counts, ssrc,
                                        bnscale, bnshift, EmbU, N);
    k_gemm<1><<<gb, 512, 0, stream>>>(HbfXlo, nullptr, EmbU, (const uint32_t*)Wpk2, bias2,
                                      nullptr, Emb, nullptr, nullptr,
                                      fcW, fcb, preds, N);
}